// Round 11
// baseline (306.730 us; speedup 1.0000x reference)
//
#include <hip/hip_runtime.h>
#include <hip/hip_bf16.h>
#include <cmath>

#define N_TOK 16384
#define D_DIM 2048
#define H_DIM 1024
#define E_DIM 64

typedef _Float16 half8 __attribute__((ext_vector_type(8)));
typedef float floatx4 __attribute__((ext_vector_type(4)));

#define GLOAD_LDS(gp, lp)                                                      \
  __builtin_amdgcn_global_load_lds(                                            \
      (const __attribute__((address_space(1))) unsigned int*)(gp),             \
      (__attribute__((address_space(3))) unsigned int*)(lp), 16, 0, 0)

// ---------------------------------------------------------------------------
// Transpose + split W1 [2048k][1024c] -> whT/wlT [1024c][2048k] f16.
// ---------------------------------------------------------------------------
__global__ __launch_bounds__(256) void splitT_w1_kernel(
    const float* __restrict__ W1, _Float16* __restrict__ whT,
    _Float16* __restrict__ wlT) {
  __shared__ float ls[64][65];
  const int k0 = blockIdx.x * 64;
  const int c0 = blockIdx.y * 64;
  const int t = threadIdx.x;
  const int tr = t >> 6;
  const int tc = t & 63;
#pragma unroll
  for (int i = 0; i < 16; i++) {
    int k = tr * 16 + i;
    ls[k][tc] = W1[(size_t)(k0 + k) * H_DIM + c0 + tc];
  }
  __syncthreads();
#pragma unroll
  for (int i = 0; i < 16; i++) {
    int c = tr * 16 + i;
    float v = ls[tc][c];
    _Float16 hv = (_Float16)v;
    _Float16 lv = (_Float16)(v - (float)hv);
    whT[(size_t)(c0 + c) * D_DIM + k0 + tc] = hv;
    wlT[(size_t)(c0 + c) * D_DIM + k0 + tc] = lv;
  }
}

// ---------------------------------------------------------------------------
// GEMM1: h = x @ W1, f16 hi/lo split, mfma 16x16x32 (0-conflict layout),
// 256x256 tile, BK=32, 512 thr (8 waves 2Mx4N), 128KB dbuf LDS.
// m201-style 4-phase/K-tile interleave:
//  ph0: dsr B(8)+A_m01(4), issue GLD_B(T+1) hi | BAR lgkm0 prio 24xMFMA BAR
//  ph1: dsr A_m23(4),      issue GLD_B(T+1) lo | ...
//  ph2: dsr A_m45(4),      issue LOAD_A(T+2)   | ...
//  ph3: dsr A_m67(4),      WRITE_A(T+1) [auto vmcnt(8) counted] | ...
//  tile end: vmcnt(4) (B(T+1) landed, A(T+2) in flight) + BAR. Never vmcnt(0)
//  in steady state.
// ---------------------------------------------------------------------------
__global__ __launch_bounds__(512, 2) void gemm1_mfma_kernel(
    const float* __restrict__ x, const _Float16* __restrict__ whT,
    const _Float16* __restrict__ wlT, float* __restrict__ h) {
  extern __shared__ __align__(16) char smem[];  // 2 x 64KB: Ah|Al|Bh|Bl

  const int t = threadIdx.x;
  const int wave = t >> 6;
  const int lane = t & 63;

  const int bid = blockIdx.x;
  const int swz = (bid & 7) * 32 + (bid >> 3);  // XCD swizzle (256 = 8*32)
  const int by = swz >> 2, bx = swz & 3;
  const int row0 = by * 256, col0 = bx * 256;
  const int wr = wave >> 2, wc = wave & 3;  // wave tile 128x64

  floatx4 acc[8][4];
#pragma unroll
  for (int m = 0; m < 8; m++)
#pragma unroll
    for (int n = 0; n < 4; n++) acc[m][n] = (floatx4){0.f, 0.f, 0.f, 0.f};

  // ---- A reg-staging (R4-verified) ----
  int awaddr[2];
  size_t gaoff[2];
#pragma unroll
  for (int q = 0; q < 2; q++) {
    const int u = q * 512 + t;
    const int arow = u >> 2;
    const int aslot = u & 3;
    awaddr[q] = arow * 64 + ((aslot ^ ((arow >> 1) & 3)) << 4);
    gaoff[q] = (size_t)(row0 + arow) * D_DIM + aslot * 8;
  }

  // ---- B gload_lds staging (R3-verified) ----
  int ldsoff[2];
  size_t gboff[2];
#pragma unroll
  for (int q = 0; q < 2; q++) {
    const int o = q * 8192 + t * 16;
    const int row = o >> 6;
    const int ss = ((o >> 4) & 3) ^ ((row >> 1) & 3);
    ldsoff[q] = q * 8192 + wave * 1024;
    gboff[q] = (size_t)(col0 + row) * D_DIM + ss * 8;
  }

  const int kg = lane >> 4;
  const int fr = lane & 15;

  // ---- fragment ds_read offsets (R4-verified, 0 conflicts) ----
  int afr[8], bfr[4];
#pragma unroll
  for (int m = 0; m < 8; m++) {
    const int r = wr * 128 + m * 16 + fr;
    afr[m] = r * 64 + ((kg ^ ((r >> 1) & 3)) << 4);
  }
#pragma unroll
  for (int n = 0; n < 4; n++) {
    const int c = wc * 64 + n * 16 + fr;
    bfr[n] = c * 64 + ((kg ^ ((c >> 1) & 3)) << 4);
  }

  float4 avA[4], avB[4];

#define LOAD_A(AV, T)                                                          \
  do {                                                                         \
    const size_t kk = (size_t)(T) * 32;                                        \
    AV[0] = *(const float4*)(x + gaoff[0] + kk);                               \
    AV[1] = *(const float4*)(x + gaoff[0] + kk + 4);                           \
    AV[2] = *(const float4*)(x + gaoff[1] + kk);                               \
    AV[3] = *(const float4*)(x + gaoff[1] + kk + 4);                           \
  } while (0)

#define WRITE_A(AV, B)                                                         \
  do {                                                                         \
    char* lb = smem + (B) * 65536;                                             \
    _Pragma("unroll") for (int q = 0; q < 2; q++) {                            \
      float vs[8] = {AV[2 * q].x, AV[2 * q].y, AV[2 * q].z, AV[2 * q].w,       \
                     AV[2 * q + 1].x, AV[2 * q + 1].y, AV[2 * q + 1].z,        \
                     AV[2 * q + 1].w};                                         \
      half8 hh, ll;                                                            \
      _Pragma("unroll") for (int j = 0; j < 8; j++) {                          \
        _Float16 hv = (_Float16)vs[j];                                         \
        hh[j] = hv;                                                            \
        ll[j] = (_Float16)(vs[j] - (float)hv);                                 \
      }                                                                        \
      *(half8*)(lb + awaddr[q]) = hh;                                          \
      *(half8*)(lb + 16384 + awaddr[q]) = ll;                                  \
    }                                                                          \
  } while (0)

#define GLD_B_HI(T)                                                            \
  do {                                                                         \
    const size_t kk = (size_t)(T) * 32;                                        \
    char* db = smem + ((T) & 1) * 65536;                                       \
    GLOAD_LDS(whT + gboff[0] + kk, db + 32768 + ldsoff[0]);                    \
    GLOAD_LDS(whT + gboff[1] + kk, db + 32768 + ldsoff[1]);                    \
  } while (0)

#define GLD_B_LO(T)                                                            \
  do {                                                                         \
    const size_t kk = (size_t)(T) * 32;                                        \
    char* db = smem + ((T) & 1) * 65536;                                       \
    GLOAD_LDS(wlT + gboff[0] + kk, db + 49152 + ldsoff[0]);                    \
    GLOAD_LDS(wlT + gboff[1] + kk, db + 49152 + ldsoff[1]);                    \
  } while (0)

#define PHASE_PRE                                                              \
  __builtin_amdgcn_sched_barrier(0);                                           \
  __builtin_amdgcn_s_barrier();                                                \
  asm volatile("s_waitcnt lgkmcnt(0)" ::: "memory");                           \
  __builtin_amdgcn_sched_barrier(0);                                           \
  __builtin_amdgcn_s_setprio(1)

#define PHASE_POST                                                             \
  __builtin_amdgcn_s_setprio(0);                                               \
  __builtin_amdgcn_sched_barrier(0);                                           \
  __builtin_amdgcn_s_barrier()

#define MM3(mm, n, AH, AL)                                                     \
  do {                                                                         \
    acc[mm][n] = __builtin_amdgcn_mfma_f32_16x16x32_f16(AH, bh[n],             \
                                                        acc[mm][n], 0, 0, 0);  \
    acc[mm][n] = __builtin_amdgcn_mfma_f32_16x16x32_f16(AH, bl[n],             \
                                                        acc[mm][n], 0, 0, 0);  \
    acc[mm][n] = __builtin_amdgcn_mfma_f32_16x16x32_f16(AL, bh[n],             \
                                                        acc[mm][n], 0, 0, 0);  \
  } while (0)

#define MPAIR(P)                                                               \
  do {                                                                         \
    _Pragma("unroll") for (int n = 0; n < 4; n++) MM3(2 * (P), n, ah0, al0);   \
    _Pragma("unroll") for (int n = 0; n < 4; n++) MM3(2 * (P) + 1, n, ah1,     \
                                                      al1);                    \
  } while (0)

  // STG: 0 steady, 1 = T=62 (no LOAD_A(T+2), end vmcnt(0)), 2 = T=63 (none)
#define BODY(T, AVL, AVW, STG)                                                 \
  do {                                                                         \
    const char* cb = smem + ((T) & 1) * 65536;                                 \
    half8 bh[4], bl[4], ah0, al0, ah1, al1;                                    \
    /* ---- phase 0 ---- */                                                    \
    _Pragma("unroll") for (int n = 0; n < 4; n++) {                            \
      bh[n] = *(const half8*)(cb + 32768 + bfr[n]);                            \
      bl[n] = *(const half8*)(cb + 49152 + bfr[n]);                            \
    }                                                                          \
    ah0 = *(const half8*)(cb + afr[0]);                                        \
    al0 = *(const half8*)(cb + 16384 + afr[0]);                                \
    ah1 = *(const half8*)(cb + afr[1]);                                        \
    al1 = *(const half8*)(cb + 16384 + afr[1]);                                \
    if ((STG) < 2) GLD_B_HI((T) + 1);                                          \
    PHASE_PRE;                                                                 \
    MPAIR(0);                                                                  \
    PHASE_POST;                                                                \
    /* ---- phase 1 ---- */                                                    \
    ah0 = *(const half8*)(cb + afr[2]);                                        \
    al0 = *(const half8*)(cb + 16384 + afr[2]);                                \
    ah1 = *(const half8*)(cb + afr[3]);                                        \
    al1 = *(const half8*)(cb + 16384 + afr[3]);                                \
    if ((STG) < 2) GLD_B_LO((T) + 1);                                          \
    PHASE_PRE;                                                                 \
    MPAIR(1);                                                                  \
    PHASE_POST;                                                                \
    /* ---- phase 2 ---- */                                                    \
    ah0 = *(const half8*)(cb + afr[4]);                                        \
    al0 = *(const half8*)(cb + 16384 + afr[4]);                                \
    ah1 = *(const half8*)(cb + afr[5]);                                        \
    al1 = *(const half8*)(cb + 16384 + afr[5]);                                \
    if ((STG) == 0) LOAD_A(AVL, (T) + 2);                                      \
    PHASE_PRE;                                                                 \
    MPAIR(2);                                                                  \
    PHASE_POST;                                                                \
    /* ---- phase 3 ---- */                                                    \
    ah0 = *(const half8*)(cb + afr[6]);                                        \
    al0 = *(const half8*)(cb + 16384 + afr[6]);                                \
    ah1 = *(const half8*)(cb + afr[7]);                                        \
    al1 = *(const half8*)(cb + 16384 + afr[7]);                                \
    if ((STG) < 2) WRITE_A(AVW, ((T) + 1) & 1); /* auto-counted vmcnt */       \
    PHASE_PRE;                                                                 \
    MPAIR(3);                                                                  \
    __builtin_amdgcn_s_setprio(0);                                             \
    __builtin_amdgcn_sched_barrier(0);                                         \
    if ((STG) == 0)                                                            \
      asm volatile("s_waitcnt vmcnt(4)" ::: "memory"); /* B(T+1) landed */     \
    else if ((STG) == 1)                                                       \
      asm volatile("s_waitcnt vmcnt(0)" ::: "memory");                         \
    if ((STG) < 2) {                                                           \
      __builtin_amdgcn_s_barrier();                                            \
      __builtin_amdgcn_sched_barrier(0);                                       \
    }                                                                          \
  } while (0)

  // ---- Prologue: stage tiles 0 (A in LDS, B gloads) and A(1) in regs ----
  LOAD_A(avA, 0);
  GLD_B_HI(0);
  GLD_B_LO(0);
  WRITE_A(avA, 0);  // auto-counted vmcnt(4): B(0) glds younger, stay in flight
  LOAD_A(avB, 1);
  __builtin_amdgcn_sched_barrier(0);
  asm volatile("s_waitcnt vmcnt(4)" ::: "memory");  // B(0) landed, A(1) flying
  asm volatile("s_waitcnt lgkmcnt(0)" ::: "memory");
  __builtin_amdgcn_s_barrier();
  __builtin_amdgcn_sched_barrier(0);

#pragma unroll 1
  for (int TT = 0; TT < 31; ++TT) {
    BODY(2 * TT, avA, avB, 0);      // even tile: load A(T+2)->avA, write avB
    BODY(2 * TT + 1, avB, avA, 0);  // odd tile: load ->avB, write avA
  }
  BODY(62, avA, avB, 1);
  BODY(63, avB, avA, 2);

#undef LOAD_A
#undef WRITE_A
#undef GLD_B_HI
#undef GLD_B_LO
#undef PHASE_PRE
#undef PHASE_POST
#undef MM3
#undef MPAIR
#undef BODY

  // Epilogue: C/D layout col=lane&15, row=(lane>>4)*4+j  [m89-verified]
  const int rj = (lane >> 4) * 4;
#pragma unroll
  for (int m = 0; m < 8; m++) {
    const int rbase = row0 + wr * 128 + m * 16 + rj;
#pragma unroll
    for (int n = 0; n < 4; n++) {
      const int c = col0 + wc * 64 + n * 16 + fr;
#pragma unroll
      for (int j = 0; j < 4; j++) {
        h[(size_t)(rbase + j) * H_DIM + c] = acc[m][n][j];
      }
    }
  }
}

// ---------------------------------------------------------------------------
// Kernel 2: per 8 tokens: +b1, LayerNorm, exact GELU, logits = g @ W2 + b2,
// softmax, top-2 (lower-index tie-break), renorm weights.
// ---------------------------------------------------------------------------
__device__ __forceinline__ float gelu_exact(float v) {
  return 0.5f * v * (1.0f + erff(v * 0.70710678118654752f));
}

__global__ __launch_bounds__(256) void router_kernel(
    const float* __restrict__ hbuf, const float* __restrict__ b1,
    const float* __restrict__ gamma, const float* __restrict__ beta,
    const float* __restrict__ W2, const float* __restrict__ b2,
    float* __restrict__ out) {
  __shared__ float g[8][H_DIM];
  __shared__ float w2s[128][E_DIM];
  __shared__ float lg[8][E_DIM];

  const int t = threadIdx.x;
  const int tok0 = blockIdx.x * 8;

  const int tk = t >> 5;
  const int l32 = t & 31;
  float vals[32];
  {
    const float* hr = hbuf + (size_t)(tok0 + tk) * H_DIM;
    float s = 0.f, s2 = 0.f;
#pragma unroll
    for (int q = 0; q < 8; q++) {
      const int j = q * 128 + l32 * 4;
      float4 v = *(const float4*)(hr + j);
      float4 bb = *(const float4*)(b1 + j);
      v.x += bb.x; v.y += bb.y; v.z += bb.z; v.w += bb.w;
      vals[q * 4 + 0] = v.x; vals[q * 4 + 1] = v.y;
      vals[q * 4 + 2] = v.z; vals[q * 4 + 3] = v.w;
      s += v.x + v.y + v.z + v.w;
      s2 += v.x * v.x + v.y * v.y + v.z * v.z + v.w * v.w;
    }
#pragma unroll
    for (int off = 16; off; off >>= 1) {
      s += __shfl_xor(s, off, 32);
      s2 += __shfl_xor(s2, off, 32);
    }
    const float mean = s * (1.f / 1024.f);
    const float var = s2 * (1.f / 1024.f) - mean * mean;
    const float rstd = rsqrtf(var + 1e-5f);
#pragma unroll
    for (int q = 0; q < 8; q++) {
      const int j = q * 128 + l32 * 4;
      float4 gm = *(const float4*)(gamma + j);
      float4 bt = *(const float4*)(beta + j);
      float4 o;
      o.x = gelu_exact((vals[q * 4 + 0] - mean) * rstd * gm.x + bt.x);
      o.y = gelu_exact((vals[q * 4 + 1] - mean) * rstd * gm.y + bt.y);
      o.z = gelu_exact((vals[q * 4 + 2] - mean) * rstd * gm.z + bt.z);
      o.w = gelu_exact((vals[q * 4 + 3] - mean) * rstd * gm.w + bt.w);
      *(float4*)&g[tk][j] = o;
    }
  }

  {
    float* lgf = &lg[0][0];
    lgf[t] = b2[t & 63];
    lgf[t + 256] = b2[t & 63];
  }

  const int seg = t >> 6;
  const int cell = t & 63;
  const int tp = cell >> 4;
  const int e0 = (cell & 15) * 4;

  float acc0[4] = {0.f, 0.f, 0.f, 0.f};
  float acc1[4] = {0.f, 0.f, 0.f, 0.f};

  for (int c = 0; c < 8; c++) {
    __syncthreads();
#pragma unroll
    for (int q = 0; q < 8; q++) {
      const int idx = q * 1024 + t * 4;
      *(float4*)(&w2s[0][0] + idx) = *(const float4*)(W2 + c * 8192 + idx);
    }
    __syncthreads();
#pragma unroll
    for (int q = 0; q < 8; q++) {
      const int i = seg * 32 + q * 4;
      float4 g0 = *(const float4*)&g[2 * tp][c * 128 + i];
      float4 g1 = *(const float4*)&g[2 * tp + 1][c * 128 + i];
      float4 w0 = *(const float4*)&w2s[i + 0][e0];
      float4 w1 = *(const float4*)&w2s[i + 1][e0];
      float4 w2v = *(const float4*)&w2s[i + 2][e0];
      float4 w3 = *(const float4*)&w2s[i + 3][e0];
      acc0[0] = fmaf(g0.x, w0.x, acc0[0]); acc0[1] = fmaf(g0.x, w0.y, acc0[1]);
      acc0[2] = fmaf(g0.x, w0.z, acc0[2]); acc0[3] = fmaf(g0.x, w0.w, acc0[3]);
      acc0[0] = fmaf(g0.y, w1.x, acc0[0]); acc0[1] = fmaf(g0.y, w1.y, acc0[1]);
      acc0[2] = fmaf(g0.y, w1.z, acc0[2]); acc0[3] = fmaf(g0.y, w1.w, acc0[3]);
      acc0[0] = fmaf(g0.z, w2v.x, acc0[0]); acc0[1] = fmaf(g0.z, w2v.y, acc0[1]);
      acc0[2] = fmaf(g0.z, w2v.z, acc0[2]); acc0[3] = fmaf(g0.z, w2v.w, acc0[3]);
      acc0[0] = fmaf(g0.w, w3.x, acc0[0]); acc0[1] = fmaf(g0.w, w3.y, acc0[1]);
      acc0[2] = fmaf(g0.w, w3.z, acc0[2]); acc0[3] = fmaf(g0.w, w3.w, acc0[3]);
      acc1[0] = fmaf(g1.x, w0.x, acc1[0]); acc1[1] = fmaf(g1.x, w0.y, acc1[1]);
      acc1[2] = fmaf(g1.x, w0.z, acc1[2]); acc1[3] = fmaf(g1.x, w0.w, acc1[3]);
      acc1[0] = fmaf(g1.y, w1.x, acc1[0]); acc1[1] = fmaf(g1.y, w1.y, acc1[1]);
      acc1[2] = fmaf(g1.y, w1.z, acc1[2]); acc1[3] = fmaf(g1.y, w1.w, acc1[3]);
      acc1[0] = fmaf(g1.z, w2v.x, acc1[0]); acc1[1] = fmaf(g1.z, w2v.y, acc1[1]);
      acc1[2] = fmaf(g1.z, w2v.z, acc1[2]); acc1[3] = fmaf(g1.z, w2v.w, acc1[3]);
      acc1[0] = fmaf(g1.w, w3.x, acc1[0]); acc1[1] = fmaf(g1.w, w3.y, acc1[1]);
      acc1[2] = fmaf(g1.w, w3.z, acc1[2]); acc1[3] = fmaf(g1.w, w3.w, acc1[3]);
    }
  }
#pragma unroll
  for (int j = 0; j < 4; j++) {
    atomicAdd(&lg[2 * tp][e0 + j], acc0[j]);
    atomicAdd(&lg[2 * tp + 1][e0 + j], acc1[j]);
  }
  __syncthreads();

  float* out_idx = out;
  float* out_w = out + 32768;
  float* out_logits = out + 65536;

  const int wv = t >> 6;
  const int lane = t & 63;
#pragma unroll
  for (int tt = 0; tt < 2; tt++) {
    const int tok = wv * 2 + tt;
    const int n = tok0 + tok;
    const float L = lg[tok][lane];
    float m = L;
#pragma unroll
    for (int off = 32; off; off >>= 1) m = fmaxf(m, __shfl_xor(m, off));
    const float ex = expf(L - m);
    float sum = ex;
#pragma unroll
    for (int off = 32; off; off >>= 1) sum += __shfl_xor(sum, off);
    const float p = ex / sum;

    float v1 = p; int i1 = lane;
#pragma unroll
    for (int off = 32; off; off >>= 1) {
      float ov = __shfl_xor(v1, off);
      int oi = __shfl_xor(i1, off);
      if (ov > v1 || (ov == v1 && oi < i1)) { v1 = ov; i1 = oi; }
    }
    float v2 = (lane == i1) ? -1.f : p; int i2 = lane;
#pragma unroll
    for (int off = 32; off; off >>= 1) {
      float ov = __shfl_xor(v2, off);
      int oi = __shfl_xor(i2, off);
      if (ov > v2 || (ov == v2 && oi < i2)) { v2 = ov; i2 = oi; }
    }

    out_logits[(size_t)n * 64 + lane] = L;
    if (lane == 0) {
      const float dn = v1 + v2 + 1e-9f;
      out_idx[n * 2 + 0] = (float)i1;
      out_idx[n * 2 + 1] = (float)i2;
      out_w[n * 2 + 0] = v1 / dn;
      out_w[n * 2 + 1] = v2 / dn;
    }
  }
}

extern "C" void kernel_launch(void* const* d_in, const int* in_sizes, int n_in,
                              void* d_out, int out_size, void* d_ws, size_t ws_size,
                              hipStream_t stream) {
  const float* x = (const float*)d_in[0];
  const float* W1 = (const float*)d_in[1];
  const float* b1 = (const float*)d_in[2];
  const float* gamma = (const float*)d_in[3];
  const float* beta = (const float*)d_in[4];
  const float* W2 = (const float*)d_in[5];
  const float* b2 = (const float*)d_in[6];
  float* out = (float*)d_out;

  char* ws = (char*)d_ws;
  _Float16* whT = (_Float16*)ws;                 // 4 MiB
  _Float16* wlT = (_Float16*)(ws + 4194304);     // 4 MiB
  float* hbuf = (float*)(ws + 8388608);          // 64 MiB (total 72 MiB)

  (void)hipFuncSetAttribute((const void*)gemm1_mfma_kernel,
                            hipFuncAttributeMaxDynamicSharedMemorySize,
                            131072);

  splitT_w1_kernel<<<dim3(D_DIM / 64, H_DIM / 64), 256, 0, stream>>>(W1, whT, wlT);

  gemm1_mfma_kernel<<<256, 512, 131072, stream>>>(x, whT, wlT, hbuf);

  router_kernel<<<N_TOK / 8, 256, 0, stream>>>(hbuf, b1, gamma, beta, W2, b2, out);
}

// Round 12
// 285.167 us; speedup vs baseline: 1.0756x; 1.0756x over previous
//
#include <hip/hip_runtime.h>
#include <hip/hip_bf16.h>
#include <cmath>

#define N_TOK 16384
#define D_DIM 2048
#define H_DIM 1024
#define E_DIM 64

typedef _Float16 half8 __attribute__((ext_vector_type(8)));
typedef float floatx4 __attribute__((ext_vector_type(4)));

#define GLOAD_LDS(gp, lp)                                                      \
  __builtin_amdgcn_global_load_lds(                                            \
      (const __attribute__((address_space(1))) unsigned int*)(gp),             \
      (__attribute__((address_space(3))) unsigned int*)(lp), 16, 0, 0)

// ---------------------------------------------------------------------------
// Transpose + split W1 [2048k][1024c] -> whT/wlT [1024c][2048k] f16.
// ---------------------------------------------------------------------------
__global__ __launch_bounds__(256) void splitT_w1_kernel(
    const float* __restrict__ W1, _Float16* __restrict__ whT,
    _Float16* __restrict__ wlT) {
  __shared__ float ls[64][65];
  const int k0 = blockIdx.x * 64;
  const int c0 = blockIdx.y * 64;
  const int t = threadIdx.x;
  const int tr = t >> 6;
  const int tc = t & 63;
#pragma unroll
  for (int i = 0; i < 16; i++) {
    int k = tr * 16 + i;
    ls[k][tc] = W1[(size_t)(k0 + k) * H_DIM + c0 + tc];
  }
  __syncthreads();
#pragma unroll
  for (int i = 0; i < 16; i++) {
    int c = tr * 16 + i;
    float v = ls[tc][c];
    _Float16 hv = (_Float16)v;
    _Float16 lv = (_Float16)(v - (float)hv);
    whT[(size_t)(c0 + c) * D_DIM + k0 + tc] = hv;
    wlT[(size_t)(c0 + c) * D_DIM + k0 + tc] = lv;
  }
}

// ---------------------------------------------------------------------------
// GEMM1: h = x @ W1, f16 hi/lo split, mfma 16x16x32 (0-conflict R4 layout),
// 256x256 tile, BK=32, 512 thr (8 waves 2Mx4N), 128KB dbuf LDS.
// R10's fully-counted pipeline: per tile GLD_B(T+1) -> MFMA cluster ->
// WRITE_A(T+1) [compiler-counted vmcnt] -> LOAD_A(T+2) -> vmcnt(4) ->
// lgkmcnt(0) -> s_barrier. No vmcnt(0) drain in steady state.
// ---------------------------------------------------------------------------
__global__ __launch_bounds__(512, 2) void gemm1_mfma_kernel(
    const float* __restrict__ x, const _Float16* __restrict__ whT,
    const _Float16* __restrict__ wlT, float* __restrict__ h) {
  extern __shared__ __align__(16) char smem[];  // 2 x 64KB: Ah|Al|Bh|Bl

  const int t = threadIdx.x;
  const int wave = t >> 6;
  const int lane = t & 63;

  const int bid = blockIdx.x;
  const int swz = (bid & 7) * 32 + (bid >> 3);  // XCD swizzle (256 = 8*32)
  const int by = swz >> 2, bx = swz & 3;
  const int row0 = by * 256, col0 = bx * 256;
  const int wr = wave >> 2, wc = wave & 3;  // wave tile 128x64

  floatx4 acc[8][4];
#pragma unroll
  for (int m = 0; m < 8; m++)
#pragma unroll
    for (int n = 0; n < 4; n++) acc[m][n] = (floatx4){0.f, 0.f, 0.f, 0.f};

  // ---- A reg-staging (R4-verified) ----
  int awaddr[2];
  size_t gaoff[2];
#pragma unroll
  for (int q = 0; q < 2; q++) {
    const int u = q * 512 + t;
    const int arow = u >> 2;
    const int aslot = u & 3;
    awaddr[q] = arow * 64 + ((aslot ^ ((arow >> 1) & 3)) << 4);
    gaoff[q] = (size_t)(row0 + arow) * D_DIM + aslot * 8;
  }

  // ---- B gload_lds staging (R3-verified) ----
  int ldsoff[2];
  size_t gboff[2];
#pragma unroll
  for (int q = 0; q < 2; q++) {
    const int o = q * 8192 + t * 16;
    const int row = o >> 6;
    const int ss = ((o >> 4) & 3) ^ ((row >> 1) & 3);
    ldsoff[q] = q * 8192 + wave * 1024;
    gboff[q] = (size_t)(col0 + row) * D_DIM + ss * 8;
  }

  const int kg = lane >> 4;
  const int fr = lane & 15;

  // ---- fragment ds_read offsets (R4-verified, 0 conflicts) ----
  int afr[8], bfr[4];
#pragma unroll
  for (int m = 0; m < 8; m++) {
    const int r = wr * 128 + m * 16 + fr;
    afr[m] = r * 64 + ((kg ^ ((r >> 1) & 3)) << 4);
  }
#pragma unroll
  for (int n = 0; n < 4; n++) {
    const int c = wc * 64 + n * 16 + fr;
    bfr[n] = c * 64 + ((kg ^ ((c >> 1) & 3)) << 4);
  }

  float4 av[2][2];

#define LOAD_A(T)                                                              \
  do {                                                                         \
    const size_t kk = (size_t)(T) * 32;                                        \
    av[0][0] = *(const float4*)(x + gaoff[0] + kk);                            \
    av[0][1] = *(const float4*)(x + gaoff[0] + kk + 4);                        \
    av[1][0] = *(const float4*)(x + gaoff[1] + kk);                            \
    av[1][1] = *(const float4*)(x + gaoff[1] + kk + 4);                        \
  } while (0)

#define WRITE_A(B)                                                             \
  do {                                                                         \
    char* lb = smem + (B) * 65536;                                             \
    _Pragma("unroll") for (int q = 0; q < 2; q++) {                            \
      float vs[8] = {av[q][0].x, av[q][0].y, av[q][0].z, av[q][0].w,           \
                     av[q][1].x, av[q][1].y, av[q][1].z, av[q][1].w};          \
      half8 hh, ll;                                                            \
      _Pragma("unroll") for (int j = 0; j < 8; j++) {                          \
        _Float16 hv = (_Float16)vs[j];                                         \
        hh[j] = hv;                                                            \
        ll[j] = (_Float16)(vs[j] - (float)hv);                                 \
      }                                                                        \
      *(half8*)(lb + awaddr[q]) = hh;                                          \
      *(half8*)(lb + 16384 + awaddr[q]) = ll;                                  \
    }                                                                          \
  } while (0)

#define GLD_B(T)                                                               \
  do {                                                                         \
    const size_t kk = (size_t)(T) * 32;                                        \
    char* db = smem + ((T) & 1) * 65536;                                       \
    GLOAD_LDS(whT + gboff[0] + kk, db + 32768 + ldsoff[0]);                    \
    GLOAD_LDS(whT + gboff[1] + kk, db + 32768 + ldsoff[1]);                    \
    GLOAD_LDS(wlT + gboff[0] + kk, db + 49152 + ldsoff[0]);                    \
    GLOAD_LDS(wlT + gboff[1] + kk, db + 49152 + ldsoff[1]);                    \
  } while (0)

  // STG: 0 = full staging (steady), 1 = no LOAD_A(T+2) (T=62), 2 = none (63)
#define BODY(T, STG)                                                           \
  do {                                                                         \
    const char* cb = smem + ((T) & 1) * 65536;                                 \
    if ((STG) < 2) GLD_B((T) + 1);                                             \
    __builtin_amdgcn_sched_barrier(0);                                         \
    half8 bh[4], bl[4];                                                        \
    _Pragma("unroll") for (int n = 0; n < 4; n++) {                            \
      bh[n] = *(const half8*)(cb + 32768 + bfr[n]);                            \
      bl[n] = *(const half8*)(cb + 49152 + bfr[n]);                            \
    }                                                                          \
    _Pragma("unroll") for (int m = 0; m < 8; m++) {                            \
      half8 ah = *(const half8*)(cb + afr[m]);                                 \
      half8 al = *(const half8*)(cb + 16384 + afr[m]);                         \
      __builtin_amdgcn_s_setprio(1);                                           \
      _Pragma("unroll") for (int n = 0; n < 4; n++) {                          \
        acc[m][n] = __builtin_amdgcn_mfma_f32_16x16x32_f16(ah, bh[n],          \
                                                           acc[m][n], 0, 0, 0);\
        acc[m][n] = __builtin_amdgcn_mfma_f32_16x16x32_f16(ah, bl[n],          \
                                                           acc[m][n], 0, 0, 0);\
        acc[m][n] = __builtin_amdgcn_mfma_f32_16x16x32_f16(al, bh[n],          \
                                                           acc[m][n], 0, 0, 0);\
      }                                                                        \
      __builtin_amdgcn_s_setprio(0);                                           \
    }                                                                          \
    __builtin_amdgcn_sched_barrier(0);                                         \
    if ((STG) < 2) {                                                           \
      WRITE_A(((T) + 1) & 1); /* av wait is counted (B gloads in flight) */    \
      if ((STG) == 0) {                                                        \
        LOAD_A((T) + 2);                                                       \
        __builtin_amdgcn_sched_barrier(0);                                     \
        asm volatile("s_waitcnt vmcnt(4)" ::: "memory"); /* B(T+1) landed */   \
      } else {                                                                 \
        __builtin_amdgcn_sched_barrier(0);                                     \
        asm volatile("s_waitcnt vmcnt(0)" ::: "memory");                       \
      }                                                                        \
      asm volatile("s_waitcnt lgkmcnt(0)" ::: "memory");                       \
      __builtin_amdgcn_s_barrier();                                            \
      __builtin_amdgcn_sched_barrier(0);                                       \
    }                                                                          \
  } while (0)

  // ---- Prologue ----
  LOAD_A(0);
  GLD_B(0);
  WRITE_A(0);  // waits A(0) regs: vmcnt(4) counted (B(0) in flight)
  LOAD_A(1);
  asm volatile("s_waitcnt vmcnt(4)" ::: "memory");  // B(0) landed, A(1) flying
  asm volatile("s_waitcnt lgkmcnt(0)" ::: "memory");
  __builtin_amdgcn_s_barrier();
  __builtin_amdgcn_sched_barrier(0);

#pragma unroll 1
  for (int T = 0; T < 62; ++T) {
    BODY(T, 0);
  }
  BODY(62, 1);
  BODY(63, 2);

#undef LOAD_A
#undef WRITE_A
#undef GLD_B
#undef BODY

  // Epilogue: C/D layout col=lane&15, row=(lane>>4)*4+j  [m89-verified]
  const int rj = (lane >> 4) * 4;
#pragma unroll
  for (int m = 0; m < 8; m++) {
    const int rbase = row0 + wr * 128 + m * 16 + rj;
#pragma unroll
    for (int n = 0; n < 4; n++) {
      const int c = col0 + wc * 64 + n * 16 + fr;
#pragma unroll
      for (int j = 0; j < 4; j++) {
        h[(size_t)(rbase + j) * H_DIM + c] = acc[m][n][j];
      }
    }
  }
}

// ---------------------------------------------------------------------------
// Kernel 2: per 8 tokens: +b1, LayerNorm, exact GELU, logits = g @ W2 + b2,
// softmax, top-2 (lower-index tie-break), renorm weights.
// ---------------------------------------------------------------------------
__device__ __forceinline__ float gelu_exact(float v) {
  return 0.5f * v * (1.0f + erff(v * 0.70710678118654752f));
}

__global__ __launch_bounds__(256) void router_kernel(
    const float* __restrict__ hbuf, const float* __restrict__ b1,
    const float* __restrict__ gamma, const float* __restrict__ beta,
    const float* __restrict__ W2, const float* __restrict__ b2,
    float* __restrict__ out) {
  __shared__ float g[8][H_DIM];
  __shared__ float w2s[128][E_DIM];
  __shared__ float lg[8][E_DIM];

  const int t = threadIdx.x;
  const int tok0 = blockIdx.x * 8;

  const int tk = t >> 5;
  const int l32 = t & 31;
  float vals[32];
  {
    const float* hr = hbuf + (size_t)(tok0 + tk) * H_DIM;
    float s = 0.f, s2 = 0.f;
#pragma unroll
    for (int q = 0; q < 8; q++) {
      const int j = q * 128 + l32 * 4;
      float4 v = *(const float4*)(hr + j);
      float4 bb = *(const float4*)(b1 + j);
      v.x += bb.x; v.y += bb.y; v.z += bb.z; v.w += bb.w;
      vals[q * 4 + 0] = v.x; vals[q * 4 + 1] = v.y;
      vals[q * 4 + 2] = v.z; vals[q * 4 + 3] = v.w;
      s += v.x + v.y + v.z + v.w;
      s2 += v.x * v.x + v.y * v.y + v.z * v.z + v.w * v.w;
    }
#pragma unroll
    for (int off = 16; off; off >>= 1) {
      s += __shfl_xor(s, off, 32);
      s2 += __shfl_xor(s2, off, 32);
    }
    const float mean = s * (1.f / 1024.f);
    const float var = s2 * (1.f / 1024.f) - mean * mean;
    const float rstd = rsqrtf(var + 1e-5f);
#pragma unroll
    for (int q = 0; q < 8; q++) {
      const int j = q * 128 + l32 * 4;
      float4 gm = *(const float4*)(gamma + j);
      float4 bt = *(const float4*)(beta + j);
      float4 o;
      o.x = gelu_exact((vals[q * 4 + 0] - mean) * rstd * gm.x + bt.x);
      o.y = gelu_exact((vals[q * 4 + 1] - mean) * rstd * gm.y + bt.y);
      o.z = gelu_exact((vals[q * 4 + 2] - mean) * rstd * gm.z + bt.z);
      o.w = gelu_exact((vals[q * 4 + 3] - mean) * rstd * gm.w + bt.w);
      *(float4*)&g[tk][j] = o;
    }
  }

  {
    float* lgf = &lg[0][0];
    lgf[t] = b2[t & 63];
    lgf[t + 256] = b2[t & 63];
  }

  const int seg = t >> 6;
  const int cell = t & 63;
  const int tp = cell >> 4;
  const int e0 = (cell & 15) * 4;

  float acc0[4] = {0.f, 0.f, 0.f, 0.f};
  float acc1[4] = {0.f, 0.f, 0.f, 0.f};

  for (int c = 0; c < 8; c++) {
    __syncthreads();
#pragma unroll
    for (int q = 0; q < 8; q++) {
      const int idx = q * 1024 + t * 4;
      *(float4*)(&w2s[0][0] + idx) = *(const float4*)(W2 + c * 8192 + idx);
    }
    __syncthreads();
#pragma unroll
    for (int q = 0; q < 8; q++) {
      const int i = seg * 32 + q * 4;
      float4 g0 = *(const float4*)&g[2 * tp][c * 128 + i];
      float4 g1 = *(const float4*)&g[2 * tp + 1][c * 128 + i];
      float4 w0 = *(const float4*)&w2s[i + 0][e0];
      float4 w1 = *(const float4*)&w2s[i + 1][e0];
      float4 w2v = *(const float4*)&w2s[i + 2][e0];
      float4 w3 = *(const float4*)&w2s[i + 3][e0];
      acc0[0] = fmaf(g0.x, w0.x, acc0[0]); acc0[1] = fmaf(g0.x, w0.y, acc0[1]);
      acc0[2] = fmaf(g0.x, w0.z, acc0[2]); acc0[3] = fmaf(g0.x, w0.w, acc0[3]);
      acc0[0] = fmaf(g0.y, w1.x, acc0[0]); acc0[1] = fmaf(g0.y, w1.y, acc0[1]);
      acc0[2] = fmaf(g0.y, w1.z, acc0[2]); acc0[3] = fmaf(g0.y, w1.w, acc0[3]);
      acc0[0] = fmaf(g0.z, w2v.x, acc0[0]); acc0[1] = fmaf(g0.z, w2v.y, acc0[1]);
      acc0[2] = fmaf(g0.z, w2v.z, acc0[2]); acc0[3] = fmaf(g0.z, w2v.w, acc0[3]);
      acc0[0] = fmaf(g0.w, w3.x, acc0[0]); acc0[1] = fmaf(g0.w, w3.y, acc0[1]);
      acc0[2] = fmaf(g0.w, w3.z, acc0[2]); acc0[3] = fmaf(g0.w, w3.w, acc0[3]);
      acc1[0] = fmaf(g1.x, w0.x, acc1[0]); acc1[1] = fmaf(g1.x, w0.y, acc1[1]);
      acc1[2] = fmaf(g1.x, w0.z, acc1[2]); acc1[3] = fmaf(g1.x, w0.w, acc1[3]);
      acc1[0] = fmaf(g1.y, w1.x, acc1[0]); acc1[1] = fmaf(g1.y, w1.y, acc1[1]);
      acc1[2] = fmaf(g1.y, w1.z, acc1[2]); acc1[3] = fmaf(g1.y, w1.w, acc1[3]);
      acc1[0] = fmaf(g1.z, w2v.x, acc1[0]); acc1[1] = fmaf(g1.z, w2v.y, acc1[1]);
      acc1[2] = fmaf(g1.z, w2v.z, acc1[2]); acc1[3] = fmaf(g1.z, w2v.w, acc1[3]);
      acc1[0] = fmaf(g1.w, w3.x, acc1[0]); acc1[1] = fmaf(g1.w, w3.y, acc1[1]);
      acc1[2] = fmaf(g1.w, w3.z, acc1[2]); acc1[3] = fmaf(g1.w, w3.w, acc1[3]);
    }
  }
#pragma unroll
  for (int j = 0; j < 4; j++) {
    atomicAdd(&lg[2 * tp][e0 + j], acc0[j]);
    atomicAdd(&lg[2 * tp + 1][e0 + j], acc1[j]);
  }
  __syncthreads();

  float* out_idx = out;
  float* out_w = out + 32768;
  float* out_logits = out + 65536;

  const int wv = t >> 6;
  const int lane = t & 63;
#pragma unroll
  for (int tt = 0; tt < 2; tt++) {
    const int tok = wv * 2 + tt;
    const int n = tok0 + tok;
    const float L = lg[tok][lane];
    float m = L;
#pragma unroll
    for (int off = 32; off; off >>= 1) m = fmaxf(m, __shfl_xor(m, off));
    const float ex = expf(L - m);
    float sum = ex;
#pragma unroll
    for (int off = 32; off; off >>= 1) sum += __shfl_xor(sum, off);
    const float p = ex / sum;

    float v1 = p; int i1 = lane;
#pragma unroll
    for (int off = 32; off; off >>= 1) {
      float ov = __shfl_xor(v1, off);
      int oi = __shfl_xor(i1, off);
      if (ov > v1 || (ov == v1 && oi < i1)) { v1 = ov; i1 = oi; }
    }
    float v2 = (lane == i1) ? -1.f : p; int i2 = lane;
#pragma unroll
    for (int off = 32; off; off >>= 1) {
      float ov = __shfl_xor(v2, off);
      int oi = __shfl_xor(i2, off);
      if (ov > v2 || (ov == v2 && oi < i2)) { v2 = ov; i2 = oi; }
    }

    out_logits[(size_t)n * 64 + lane] = L;
    if (lane == 0) {
      const float dn = v1 + v2 + 1e-9f;
      out_idx[n * 2 + 0] = (float)i1;
      out_idx[n * 2 + 1] = (float)i2;
      out_w[n * 2 + 0] = v1 / dn;
      out_w[n * 2 + 1] = v2 / dn;
    }
  }
}

extern "C" void kernel_launch(void* const* d_in, const int* in_sizes, int n_in,
                              void* d_out, int out_size, void* d_ws, size_t ws_size,
                              hipStream_t stream) {
  const float* x = (const float*)d_in[0];
  const float* W1 = (const float*)d_in[1];
  const float* b1 = (const float*)d_in[2];
  const float* gamma = (const float*)d_in[3];
  const float* beta = (const float*)d_in[4];
  const float* W2 = (const float*)d_in[5];
  const float* b2 = (const float*)d_in[6];
  float* out = (float*)d_out;

  char* ws = (char*)d_ws;
  _Float16* whT = (_Float16*)ws;                 // 4 MiB
  _Float16* wlT = (_Float16*)(ws + 4194304);     // 4 MiB
  float* hbuf = (float*)(ws + 8388608);          // 64 MiB (total 72 MiB)

  (void)hipFuncSetAttribute((const void*)gemm1_mfma_kernel,
                            hipFuncAttributeMaxDynamicSharedMemorySize,
                            131072);

  splitT_w1_kernel<<<dim3(D_DIM / 64, H_DIM / 64), 256, 0, stream>>>(W1, whT, wlT);

  gemm1_mfma_kernel<<<256, 512, 131072, stream>>>(x, whT, wlT, hbuf);

  router_kernel<<<N_TOK / 8, 256, 0, stream>>>(hbuf, b1, gamma, beta, W2, b2, out);
}